// Round 14
// baseline (1155.903 us; speedup 1.0000x reference)
//
#include <hip/hip_runtime.h>
#include <hip/hip_bf16.h>

// ---------------- constants (Swin block geometry) ----------------
#define C_DIM   384
#define HEADS   12
#define HDIM    32
#define NTOK    49
#define TOT_WIN 2048        // 32 images * 64 windows
#define M_TOK   100352      // TOT_WIN*49
#define QKV_N   1152
#define MLP_N   1536
#define SHIFT_V 3

typedef __bf16 bf16x8_t __attribute__((ext_vector_type(8)));
typedef float  f32x4_t  __attribute__((ext_vector_type(4)));

__device__ inline float b2f(ushort u) {
    union { unsigned u; float f; } p; p.u = ((unsigned)u) << 16; return p.f;
}
__device__ inline ushort f2b(float f) {
    union { float f; unsigned u; } p; p.f = f;
    unsigned r = p.u + 0x7FFF + ((p.u >> 16) & 1);
    return (ushort)(r >> 16);
}
// dtype-branched scalar load from a native input buffer
__device__ inline float ldin(const void* p, size_t i, int dt) {
    return dt ? b2f(((const ushort*)p)[i]) : ((const float*)p)[i];
}

__device__ inline void gload_lds16(const ushort* g, ushort* l) {
    __builtin_amdgcn_global_load_lds(
        (__attribute__((address_space(1))) void*)const_cast<ushort*>(g),
        (__attribute__((address_space(3))) void*)l, 16, 0, 0);
}

// windowed-token index (global) -> original token row (shift roll, +3 mod 56)
__device__ inline int win2tok(int grow) {
    int widx = grow / 49, tok = grow - widx * 49;
    int b = widx >> 6, w_ = widx & 63;
    int wh = w_ >> 3, ww = w_ & 7;
    int r = tok / 7, c = tok - r * 7;
    int h = wh * 7 + r + SHIFT_V; if (h >= 56) h -= 56;
    int wc = ww * 7 + c + SHIFT_V; if (wc >= 56) wc -= 56;
    return b * 3136 + h * 56 + wc;
}

// ---------------- dtype sniffer: even-index ushorts sane-bf16 test ----------------
__global__ void sniff_kernel(const ushort* x16, int* flag) {
    const int tid = threadIdx.x;
    int cnt = 0;
    for (int i = tid; i < 4096; i += 256) {
        ushort u = x16[2 * i];
        int e = (u >> 7) & 0xFF;
        if ((u & 0x7FFF) == 0 || (e >= 107 && e <= 147)) cnt++;
    }
    __shared__ int ss[256];
    ss[tid] = cnt; __syncthreads();
    for (int s = 128; s; s >>= 1) { if (tid < s) ss[tid] += ss[tid + s]; __syncthreads(); }
    if (tid == 0) *flag = (ss[0] >= 2048) ? 1 : 0;   // 1 = bf16 storage, 0 = f32 storage
}

// ---------------- weight convert: native -> canonical bf16 ----------------
__global__ void cvt_w_kernel(const void* src, ushort* dst, int n, const int* flagp) {
    const int dt = *flagp;
    for (int i = blockIdx.x * blockDim.x + threadIdx.x; i < n; i += gridDim.x * blockDim.x)
        dst[i] = dt ? ((const ushort*)src)[i] : f2b(((const float*)src)[i]);
}

// ---------------- small params -> canonical f32 (concatenated) ----------------
// floats: n1g 0 | n1b 384 | qkv_b 768 | proj_b 1920 | n2g 2304 | n2b 2688 |
//         fc1_b 3072 | fc2_b 4608 | rpb 4992..7020
__global__ void cvt_p_kernel(const void* n1g, const void* n1b, const void* qkvb,
                             const void* projb, const void* n2g, const void* n2b,
                             const void* fc1b, const void* fc2b, const void* rpb,
                             float* prm, const int* flagp) {
    const int dt = *flagp;
    for (int i = threadIdx.x; i < 7020; i += 256) {
        float v;
        if      (i < 384)  v = ldin(n1g,  i,        dt);
        else if (i < 768)  v = ldin(n1b,  i - 384,  dt);
        else if (i < 1920) v = ldin(qkvb, i - 768,  dt);
        else if (i < 2304) v = ldin(projb,i - 1920, dt);
        else if (i < 2688) v = ldin(n2g,  i - 2304, dt);
        else if (i < 3072) v = ldin(n2b,  i - 2688, dt);
        else if (i < 4608) v = ldin(fc1b, i - 3072, dt);
        else if (i < 4992) v = ldin(fc2b, i - 4608, dt);
        else               v = ldin(rpb,  i - 4992, dt);
        prm[i] = v;
    }
}

// ---------------- LayerNorm ----------------
// MODE 0: gather shift+window-partition from native x (dt-branched)
// MODE 2: plain rows moff+m from bf16 buffer (x2b)
template<int MODE>
__global__ __launch_bounds__(256) void ln_kernel(
    const void* __restrict__ x, const float* __restrict__ g,
    const float* __restrict__ b, ushort* __restrict__ out,
    const int* flagp, int moff)
{
    const int dt = *flagp;
    const int wid = threadIdx.x >> 6, lane = threadIdx.x & 63;
    const int m = blockIdx.x * 4 + wid;
    const int src = (MODE == 0) ? win2tok(moff + m) : (moff + m);

    float v[6]; float s = 0.f, sq = 0.f;
    #pragma unroll
    for (int k = 0; k < 6; ++k) {
        size_t idx = (size_t)src * C_DIM + lane + 64 * k;
        v[k] = (MODE == 2) ? b2f(((const ushort*)x)[idx]) : ldin(x, idx, dt);
        s += v[k]; sq += v[k] * v[k];
    }
    #pragma unroll
    for (int off = 32; off; off >>= 1) {
        s  += __shfl_xor(s,  off, 64);
        sq += __shfl_xor(sq, off, 64);
    }
    float mean = s * (1.f / 384.f);
    float var  = sq * (1.f / 384.f) - mean * mean;
    float rstd = rsqrtf(var + 1e-5f);
    #pragma unroll
    for (int k = 0; k < 6; ++k) {
        int col = lane + 64 * k;
        out[(size_t)m * C_DIM + col] =
            f2b((v[k] - mean) * rstd * g[col] + b[col]);
    }
}

// ---------------- GEMM: depth-3 counted-vmcnt pipeline; bn on blockIdx.x (fast) -------
// Step kt: STAGE(kt+2 -> buf[(kt+2)%3]) ; vmcnt(8) [kt landed; kt+1,kt+2 in flight] ;
// s_barrier ; compute(buf[kt%3]) ; s_barrier. Stage at kt writes buf[(kt-1)%3]'s slot,
// whose readers finished at kt-1's trailing barrier -> race-free. Prefetch distance
// = 2 compute phases (~2x deeper than round 10). LDS 48KB -> 3 blocks/CU.
// MODE 0: QKV->bf16 | 1: PROJ scatter: x2b(bf16) = v + resid(native x) |
// 2: FC1+GELU->bf16 | 3: FC2: out(native dtype) = v + resid(bf16 x2b)
template<int MODE>
__global__ __launch_bounds__(256, 2) void gemm_bt(
    const ushort* __restrict__ A, const ushort* __restrict__ W,
    const float* __restrict__ bias, ushort* outb, void* outv,
    const void* resid, const int* flagp, int N, int K, int Mrows, int moff)
{
    __shared__ __align__(16) ushort As[3][128 * 32];
    __shared__ __align__(16) ushort Bs[3][128 * 32];

    const int dt   = *flagp;
    const int tid  = threadIdx.x;
    const int wid  = tid >> 6;
    const int lane = tid & 63;
    const int bm = blockIdx.y * 128;     // rows: y (slow)
    const int bn = blockIdx.x * 128;     // cols: x (fast) -> A-tile sharers adjacent
    const int wm = (wid >> 1) * 64;
    const int wn = (wid & 1) * 64;
    const int lrow = lane & 15;
    const int lk   = (lane >> 4) << 3;

    const int c0    = wid * 2;
    const int srow0 = c0 * 16 + (lane >> 2);
    const int srow1 = srow0 + 16;
    const int skoff = (lane & 3) << 3;

    const int ar0 = (bm + srow0 < Mrows) ? (bm + srow0) : (Mrows - 1);
    const int ar1 = (bm + srow1 < Mrows) ? (bm + srow1) : (Mrows - 1);

    const ushort* pa0 = A + (size_t)ar0 * K + skoff;
    const ushort* pa1 = A + (size_t)ar1 * K + skoff;
    const ushort* pb0 = W + (size_t)(bn + srow0) * K + skoff;
    const ushort* pb1 = W + (size_t)(bn + srow1) * K + skoff;

    // bias preload BEFORE staging (extra VMEM entries only make vmcnt counts conservative)
    float biasf[4]; int coln[4];
    #pragma unroll
    for (int n = 0; n < 4; ++n) {
        coln[n] = bn + wn + n * 16 + lrow;
        biasf[n] = bias[coln[n]];
    }

    f32x4_t acc[4][4];
    #pragma unroll
    for (int m = 0; m < 4; ++m)
        #pragma unroll
        for (int n = 0; n < 4; ++n) acc[m][n] = (f32x4_t){0.f, 0.f, 0.f, 0.f};

    const int nk = K >> 5;   // always >= 12 here
    // prologue: stage steps 0 and 1
    gload_lds16(pa0,      As[0] + (c0)     * 512);
    gload_lds16(pa1,      As[0] + (c0 + 1) * 512);
    gload_lds16(pb0,      Bs[0] + (c0)     * 512);
    gload_lds16(pb1,      Bs[0] + (c0 + 1) * 512);
    gload_lds16(pa0 + 32, As[1] + (c0)     * 512);
    gload_lds16(pa1 + 32, As[1] + (c0 + 1) * 512);
    gload_lds16(pb0 + 32, Bs[1] + (c0)     * 512);
    gload_lds16(pb1 + 32, Bs[1] + (c0 + 1) * 512);

    int cur = 0, stg = 2;
    for (int kt = 0; kt < nk; ++kt) {
        if (kt + 2 < nk) {
            const int k2 = (kt + 2) << 5;
            gload_lds16(pa0 + k2, As[stg] + (c0)     * 512);
            gload_lds16(pa1 + k2, As[stg] + (c0 + 1) * 512);
            gload_lds16(pb0 + k2, Bs[stg] + (c0)     * 512);
            gload_lds16(pb1 + k2, Bs[stg] + (c0 + 1) * 512);
            __builtin_amdgcn_sched_barrier(0);
            asm volatile("s_waitcnt vmcnt(8)" ::: "memory");  // kt landed; kt+1,kt+2 in flight
        } else if (kt + 1 < nk) {
            __builtin_amdgcn_sched_barrier(0);
            asm volatile("s_waitcnt vmcnt(4)" ::: "memory");  // kt landed; kt+1 in flight
        } else {
            asm volatile("s_waitcnt vmcnt(0)" ::: "memory");
        }
        __builtin_amdgcn_s_barrier();        // buf[cur] populated block-wide
        __builtin_amdgcn_sched_barrier(0);

        bf16x8_t af[4], bfr[4];
        #pragma unroll
        for (int m = 0; m < 4; ++m)
            af[m] = *(const bf16x8_t*)&As[cur][(wm + m * 16 + lrow) * 32 + lk];
        #pragma unroll
        for (int n = 0; n < 4; ++n)
            bfr[n] = *(const bf16x8_t*)&Bs[cur][(wn + n * 16 + lrow) * 32 + lk];
        #pragma unroll
        for (int m = 0; m < 4; ++m)
            #pragma unroll
            for (int n = 0; n < 4; ++n)
                acc[m][n] = __builtin_amdgcn_mfma_f32_16x16x32_bf16(
                    af[m], bfr[n], acc[m][n], 0, 0, 0);

        __builtin_amdgcn_sched_barrier(0);
        __builtin_amdgcn_s_barrier();        // all reads of buf[cur] done
        cur = (cur == 2) ? 0 : cur + 1;
        stg = (stg == 2) ? 0 : stg + 1;
    }

    const int rbase = bm + wm + ((lane >> 4) << 2);
    #pragma unroll
    for (int m = 0; m < 4; ++m) {
        #pragma unroll
        for (int j = 0; j < 4; ++j) {
            int grow = rbase + m * 16 + j;
            if (grow >= Mrows) continue;
            #pragma unroll
            for (int n = 0; n < 4; ++n) {
                float v = acc[m][n][j] + biasf[n];
                if (MODE == 0) {
                    outb[(size_t)grow * N + coln[n]] = f2b(v);
                } else if (MODE == 2) {
                    v = 0.5f * v * (1.0f + erff(v * 0.70710678118654752f));
                    outb[(size_t)grow * N + coln[n]] = f2b(v);
                } else if (MODE == 1) {
                    // x2(bf16) = proj + shortcut(native x); scattered row
                    size_t oidx = (size_t)win2tok(moff + grow) * (size_t)N + coln[n];
                    outb[oidx] = f2b(v + ldin(resid, oidx, dt));
                } else {
                    // FC2: out(native) = v + x2b(bf16); rows moff+grow
                    size_t oidx = (size_t)(moff + grow) * (size_t)N + coln[n];
                    float r = v + b2f(((const ushort*)resid)[oidx]);
                    if (dt) ((ushort*)outv)[oidx] = f2b(r);
                    else    ((float*) outv)[oidx] = r;
                }
            }
        }
    }
}

// ---------------- MFMA windowed attention: 1 block/window, wave = 3 heads ----------------
__global__ __launch_bounds__(256) void attn_kernel(
    const ushort* __restrict__ qkv, const float* __restrict__ rpb,
    ushort* __restrict__ out, int win_off)
{
    __shared__ __align__(16) ushort Pl[4][64 * 64];   // 8KB per wave
    __shared__ __align__(16) ushort Vtl[4][32 * 64];  // 4KB per wave

    const int tid = threadIdx.x, wid = tid >> 6, lane = tid & 63;
    const int lo = lane & 15, hi = lane >> 4;
    const int widx = blockIdx.x;
    const int w_ = (win_off + widx) & 63;
    const int wh = w_ >> 3, ww = w_ & 7;
    const bool edge = (wh == 7) || (ww == 7);

    char* P  = (char*)Pl[wid];
    char* Vw = (char*)Vtl[wid];

    int qr[4], qc[4], rq[4];
    #pragma unroll
    for (int n = 0; n < 4; ++n) {
        int q = n * 16 + lo; if (q > 48) q = 48;
        qr[n] = q / 7; qc[n] = q - qr[n] * 7;
        int gh = wh * 7 + qr[n], gw = ww * 7 + qc[n];
        rq[n] = (gh < 49 ? 0 : (gh < 53 ? 1 : 2)) * 3 + (gw < 49 ? 0 : (gw < 53 ? 1 : 2));
    }

    for (int h = wid; h < HEADS; h += 4) {
        const size_t hb = (size_t)widx * 49 * QKV_N + h * HDIM;

        bf16x8_t kf[4], qf[4];
        #pragma unroll
        for (int t = 0; t < 4; ++t) {
            int r = t * 16 + lo;
            bf16x8_t z = {};
            kf[t] = z; qf[t] = z;
            if (r < 49) {
                kf[t] = *(const bf16x8_t*)(qkv + hb + (size_t)r * QKV_N + 384 + hi * 8);
                qf[t] = *(const bf16x8_t*)(qkv + hb + (size_t)r * QKV_N + hi * 8);
            }
        }

        {
            const int kk = lane;
            union { bf16x8_t v; ushort u[8]; } vv[4];
            #pragma unroll
            for (int c = 0; c < 4; ++c) {
                bf16x8_t z = {};
                vv[c].v = (kk < 49) ? *(const bf16x8_t*)(qkv + hb + (size_t)kk * QKV_N + 768 + c * 8)
                                    : z;
            }
            #pragma unroll
            for (int d = 0; d < 32; ++d) {
                int byo = (d * 128 + kk * 2) ^ ((d & 7) << 4);
                *(ushort*)(Vw + byo) = vv[d >> 3].u[d & 7];
            }
        }

        f32x4_t St[4][4];
        #pragma unroll
        for (int m = 0; m < 4; ++m)
            #pragma unroll
            for (int n = 0; n < 4; ++n) St[m][n] = (f32x4_t){0.f, 0.f, 0.f, 0.f};
        #pragma unroll
        for (int m = 0; m < 4; ++m)
            #pragma unroll
            for (int n = 0; n < 4; ++n)
                St[m][n] = __builtin_amdgcn_mfma_f32_16x16x32_bf16(kf[m], qf[n], St[m][n], 0, 0, 0);

        #pragma unroll
        for (int m = 0; m < 4; ++m) {
            #pragma unroll
            for (int j = 0; j < 4; ++j) {
                const int kk = m * 16 + hi * 4 + j;
                const int kcl = (kk > 48) ? 48 : kk;
                const int kr = kcl / 7, kc = kcl - kr * 7;
                int rk = 0;
                if (edge) {
                    int gh = wh * 7 + kr, gw = ww * 7 + kc;
                    rk = (gh < 49 ? 0 : (gh < 53 ? 1 : 2)) * 3 + (gw < 49 ? 0 : (gw < 53 ? 1 : 2));
                }
                #pragma unroll
                for (int n = 0; n < 4; ++n) {
                    int idx = (qr[n] - kr + 6) * 13 + (qc[n] - kc + 6);
                    float v = St[m][n][j] * 0.17677669529663687f + rpb[idx * 12 + h];
                    if (edge && (rq[n] != rk)) v -= 100.f;
                    if (kk > 48) v = -1e30f;
                    St[m][n][j] = v;
                }
            }
        }

        float sm[4];
        #pragma unroll
        for (int n = 0; n < 4; ++n) {
            float mv = St[0][n][0];
            #pragma unroll
            for (int m = 0; m < 4; ++m)
                #pragma unroll
                for (int j = 0; j < 4; ++j) mv = fmaxf(mv, St[m][n][j]);
            mv = fmaxf(mv, __shfl_xor(mv, 16, 64));
            mv = fmaxf(mv, __shfl_xor(mv, 32, 64));
            float sv = 0.f;
            #pragma unroll
            for (int m = 0; m < 4; ++m)
                #pragma unroll
                for (int j = 0; j < 4; ++j) {
                    float e = __expf(St[m][n][j] - mv);
                    St[m][n][j] = e; sv += e;
                }
            sv += __shfl_xor(sv, 16, 64);
            sv += __shfl_xor(sv, 32, 64);
            sm[n] = 1.f / sv;
        }

        #pragma unroll
        for (int m = 0; m < 4; ++m) {
            #pragma unroll
            for (int n = 0; n < 4; ++n) {
                union { ushort4 u4; __bf16 b[4]; } pk;
                #pragma unroll
                for (int j = 0; j < 4; ++j) pk.b[j] = (__bf16)(St[m][n][j] * sm[n]);
                int byo = ((n * 16 + lo) * 128 + (m * 16 + hi * 4) * 2) ^ ((lo & 7) << 4);
                *(ushort4*)(P + byo) = pk.u4;
            }
        }

        f32x4_t Oa[4][2];
        #pragma unroll
        for (int mt = 0; mt < 4; ++mt)
            #pragma unroll
            for (int nt = 0; nt < 2; ++nt) Oa[mt][nt] = (f32x4_t){0.f, 0.f, 0.f, 0.f};
        #pragma unroll
        for (int s = 0; s < 2; ++s) {
            bf16x8_t vf[2];
            #pragma unroll
            for (int nt = 0; nt < 2; ++nt) {
                int byo = ((nt * 16 + lo) * 128 + s * 64 + hi * 16) ^ ((lo & 7) << 4);
                vf[nt] = *(const bf16x8_t*)(Vw + byo);
            }
            #pragma unroll
            for (int mt = 0; mt < 4; ++mt) {
                int byo = ((mt * 16 + lo) * 128 + s * 64 + hi * 16) ^ ((lo & 7) << 4);
                bf16x8_t pf = *(const bf16x8_t*)(P + byo);
                #pragma unroll
                for (int nt = 0; nt < 2; ++nt)
                    Oa[mt][nt] = __builtin_amdgcn_mfma_f32_16x16x32_bf16(pf, vf[nt], Oa[mt][nt], 0, 0, 0);
            }
        }

        #pragma unroll
        for (int mt = 0; mt < 4; ++mt) {
            #pragma unroll
            for (int j = 0; j < 4; ++j) {
                int q = mt * 16 + hi * 4 + j;
                if (q < 49) {
                    size_t ro = ((size_t)(widx * 49 + q)) * C_DIM + h * HDIM;
                    #pragma unroll
                    for (int nt = 0; nt < 2; ++nt)
                        out[ro + nt * 16 + lo] = f2b(Oa[mt][nt][j]);
                }
            }
        }
    }
}

// ---------------- launch ----------------
extern "C" void kernel_launch(void* const* d_in, const int* in_sizes, int n_in,
                              void* d_out, int out_size, void* d_ws, size_t ws_size,
                              hipStream_t stream)
{
    const void* x      = d_in[0];
    const void* n1g    = d_in[3];
    const void* n1b    = d_in[4];
    const void* qkv_w  = d_in[5];
    const void* qkv_b  = d_in[6];
    const void* rpb    = d_in[7];
    const void* proj_w = d_in[8];
    const void* proj_b = d_in[9];
    const void* n2g    = d_in[10];
    const void* n2b    = d_in[11];
    const void* fc1_w  = d_in[12];
    const void* fc1_b  = d_in[13];
    const void* fc2_w  = d_in[14];
    const void* fc2_b  = d_in[15];

    // ws: 0 flag | 256 prm f32 | 28416 weights bf16 | WSTATIC: x2b (full, bf16) | ws0 | ws1
    int*    flagp = (int*)d_ws;
    float*  prm   = (float*)((char*)d_ws + 256);
    ushort* wq    = (ushort*)((char*)d_ws + 28416);
    ushort* wp    = wq + 442368;
    ushort* w1m   = wp + 147456;
    ushort* w2m   = w1m + 589824;
    const size_t WSTATIC = 3567360;
    const size_t X2B_B   = 77070336ull;               // M_TOK*384*2

    int nc = 64;
    const int opts[7] = {1, 2, 4, 8, 16, 32, 64};
    for (int i = 0; i < 7; ++i) {
        size_t need = WSTATIC + X2B_B + ((size_t)M_TOK / opts[i]) * 3840ull;
        if (need <= ws_size) { nc = opts[i]; break; }
    }
    const int wins_pc = TOT_WIN / nc;
    const int rows_pc = wins_pc * NTOK;
    const int gx      = (rows_pc + 127) / 128;

    ushort* x2b = (ushort*)((char*)d_ws + WSTATIC);   // full M_TOK x 384 bf16
    ushort* ws0 = x2b + (size_t)M_TOK * C_DIM;
    ushort* ws1 = ws0 + (size_t)rows_pc * C_DIM;

    sniff_kernel<<<1, 256, 0, stream>>>((const ushort*)x, flagp);
    cvt_p_kernel<<<1, 256, 0, stream>>>(n1g, n1b, qkv_b, proj_b, n2g, n2b,
                                        fc1_b, fc2_b, rpb, prm, flagp);
    cvt_w_kernel<<<432, 256, 0, stream>>>(qkv_w,  wq,  442368, flagp);
    cvt_w_kernel<<<144, 256, 0, stream>>>(proj_w, wp,  147456, flagp);
    cvt_w_kernel<<<576, 256, 0, stream>>>(fc1_w,  w1m, 589824, flagp);
    cvt_w_kernel<<<576, 256, 0, stream>>>(fc2_w,  w2m, 589824, flagp);

    const float* b_qkv = prm + 768;
    const float* b_prj = prm + 1920;
    const float* b_fc1 = prm + 3072;
    const float* b_fc2 = prm + 4608;
    const float* rpb_c = prm + 4992;

    for (int c = 0; c < nc; ++c) {
        const int moff = c * rows_pc;
        ln_kernel<0><<<rows_pc / 4, 256, 0, stream>>>(x, prm + 0, prm + 384, ws0, flagp, moff);
        gemm_bt<0><<<dim3(9, gx), 256, 0, stream>>>(
            ws0, wq, b_qkv, ws1, nullptr, nullptr, flagp, QKV_N, C_DIM, rows_pc, 0);
        attn_kernel<<<wins_pc, 256, 0, stream>>>(ws1, rpb_c, ws0, c * wins_pc);
        // PROJ: x2b(bf16, scattered global rows) = proj(attn) + shortcut(native x)
        gemm_bt<1><<<dim3(3, gx), 256, 0, stream>>>(
            ws0, wp, b_prj, x2b, nullptr, x, flagp, C_DIM, C_DIM, rows_pc, moff);
    }

    for (int c = 0; c < nc; ++c) {
        const int moff = c * rows_pc;
        // LN2 reads bf16 x2b (global rows moff+m)
        ln_kernel<2><<<rows_pc / 4, 256, 0, stream>>>(x2b, prm + 2304, prm + 2688, ws0, flagp, moff);
        gemm_bt<2><<<dim3(12, gx), 256, 0, stream>>>(
            ws0, w1m, b_fc1, ws1, nullptr, nullptr, flagp, MLP_N, C_DIM, rows_pc, 0);
        // FC2: d_out(native, global rows moff+grow) = fc2(h1) + x2b(bf16)
        gemm_bt<3><<<dim3(3, gx), 256, 0, stream>>>(
            ws1, w2m, b_fc2, nullptr, d_out, x2b, flagp, C_DIM, MLP_N, rows_pc, moff);
    }
}

// Round 15
// 1099.246 us; speedup vs baseline: 1.0515x; 1.0515x over previous
//
#include <hip/hip_runtime.h>
#include <hip/hip_bf16.h>

// ---------------- constants (Swin block geometry) ----------------
#define C_DIM   384
#define HEADS   12
#define HDIM    32
#define NTOK    49
#define TOT_WIN 2048        // 32 images * 64 windows
#define M_TOK   100352      // TOT_WIN*49
#define QKV_N   1152
#define MLP_N   1536
#define SHIFT_V 3

typedef __bf16 bf16x8_t __attribute__((ext_vector_type(8)));
typedef float  f32x4_t  __attribute__((ext_vector_type(4)));

__device__ inline float b2f(ushort u) {
    union { unsigned u; float f; } p; p.u = ((unsigned)u) << 16; return p.f;
}
__device__ inline ushort f2b(float f) {
    union { float f; unsigned u; } p; p.f = f;
    unsigned r = p.u + 0x7FFF + ((p.u >> 16) & 1);
    return (ushort)(r >> 16);
}
// dtype-branched scalar load from a native input buffer
__device__ inline float ldin(const void* p, size_t i, int dt) {
    return dt ? b2f(((const ushort*)p)[i]) : ((const float*)p)[i];
}

__device__ inline void gload_lds16(const ushort* g, ushort* l) {
    __builtin_amdgcn_global_load_lds(
        (__attribute__((address_space(1))) void*)const_cast<ushort*>(g),
        (__attribute__((address_space(3))) void*)l, 16, 0, 0);
}

// windowed-token index (global) -> original token row (shift roll, +3 mod 56)
__device__ inline int win2tok(int grow) {
    int widx = grow / 49, tok = grow - widx * 49;
    int b = widx >> 6, w_ = widx & 63;
    int wh = w_ >> 3, ww = w_ & 7;
    int r = tok / 7, c = tok - r * 7;
    int h = wh * 7 + r + SHIFT_V; if (h >= 56) h -= 56;
    int wc = ww * 7 + c + SHIFT_V; if (wc >= 56) wc -= 56;
    return b * 3136 + h * 56 + wc;
}

// ---------------- dtype sniffer: even-index ushorts sane-bf16 test ----------------
__global__ void sniff_kernel(const ushort* x16, int* flag) {
    const int tid = threadIdx.x;
    int cnt = 0;
    for (int i = tid; i < 4096; i += 256) {
        ushort u = x16[2 * i];
        int e = (u >> 7) & 0xFF;
        if ((u & 0x7FFF) == 0 || (e >= 107 && e <= 147)) cnt++;
    }
    __shared__ int ss[256];
    ss[tid] = cnt; __syncthreads();
    for (int s = 128; s; s >>= 1) { if (tid < s) ss[tid] += ss[tid + s]; __syncthreads(); }
    if (tid == 0) *flag = (ss[0] >= 2048) ? 1 : 0;   // 1 = bf16 storage, 0 = f32 storage
}

// ---------------- weight convert: native -> canonical bf16 ----------------
__global__ void cvt_w_kernel(const void* src, ushort* dst, int n, const int* flagp) {
    const int dt = *flagp;
    for (int i = blockIdx.x * blockDim.x + threadIdx.x; i < n; i += gridDim.x * blockDim.x)
        dst[i] = dt ? ((const ushort*)src)[i] : f2b(((const float*)src)[i]);
}

// ---------------- small params -> canonical f32 (concatenated) ----------------
// floats: n1g 0 | n1b 384 | qkv_b 768 | proj_b 1920 | n2g 2304 | n2b 2688 |
//         fc1_b 3072 | fc2_b 4608 | rpb 4992..7020
__global__ void cvt_p_kernel(const void* n1g, const void* n1b, const void* qkvb,
                             const void* projb, const void* n2g, const void* n2b,
                             const void* fc1b, const void* fc2b, const void* rpb,
                             float* prm, const int* flagp) {
    const int dt = *flagp;
    for (int i = threadIdx.x; i < 7020; i += 256) {
        float v;
        if      (i < 384)  v = ldin(n1g,  i,        dt);
        else if (i < 768)  v = ldin(n1b,  i - 384,  dt);
        else if (i < 1920) v = ldin(qkvb, i - 768,  dt);
        else if (i < 2304) v = ldin(projb,i - 1920, dt);
        else if (i < 2688) v = ldin(n2g,  i - 2304, dt);
        else if (i < 3072) v = ldin(n2b,  i - 2688, dt);
        else if (i < 4608) v = ldin(fc1b, i - 3072, dt);
        else if (i < 4992) v = ldin(fc2b, i - 4608, dt);
        else               v = ldin(rpb,  i - 4992, dt);
        prm[i] = v;
    }
}

// ---------------- LayerNorm ----------------
// MODE 0: gather shift+window-partition from native x (dt-branched)
// MODE 2: plain rows moff+m from bf16 buffer (x2b)
template<int MODE>
__global__ __launch_bounds__(256) void ln_kernel(
    const void* __restrict__ x, const float* __restrict__ g,
    const float* __restrict__ b, ushort* __restrict__ out,
    const int* flagp, int moff)
{
    const int dt = *flagp;
    const int wid = threadIdx.x >> 6, lane = threadIdx.x & 63;
    const int m = blockIdx.x * 4 + wid;
    const int src = (MODE == 0) ? win2tok(moff + m) : (moff + m);

    float v[6]; float s = 0.f, sq = 0.f;
    #pragma unroll
    for (int k = 0; k < 6; ++k) {
        size_t idx = (size_t)src * C_DIM + lane + 64 * k;
        v[k] = (MODE == 2) ? b2f(((const ushort*)x)[idx]) : ldin(x, idx, dt);
        s += v[k]; sq += v[k] * v[k];
    }
    #pragma unroll
    for (int off = 32; off; off >>= 1) {
        s  += __shfl_xor(s,  off, 64);
        sq += __shfl_xor(sq, off, 64);
    }
    float mean = s * (1.f / 384.f);
    float var  = sq * (1.f / 384.f) - mean * mean;
    float rstd = rsqrtf(var + 1e-5f);
    #pragma unroll
    for (int k = 0; k < 6; ++k) {
        int col = lane + 64 * k;
        out[(size_t)m * C_DIM + col] =
            f2b((v[k] - mean) * rstd * g[col] + b[col]);
    }
}

// ---------------- GEMM: 256x128 tile, 8 waves, depth-2 counted-vmcnt(3) ----------------
// Geometry change on the round-10-verified sync structure: BM=256 (8 waves, wave grid
// 4m x 2n, 64x64/wave), BK=32, LDS = 2*(A 16KB + B 8KB) = 48KB -> 3 blocks/CU =
// 24 waves/CU (2x round 14's 12).  Staging: thread owns 16B chunks {tid, tid+512} of A
// and {tid} of B; dest = wave-uniform + lane*16 (chunk=tid => off = wid*1024+lane*16).
// 3 loads/thread/step => vmcnt(3) == prev stage exactly.  Two-barrier race proof as r10.
// MODE 0: QKV->bf16 | 1: PROJ scatter: x2b(bf16) = v + resid(native x) |
// 2: FC1+GELU->bf16 | 3: FC2: out(native dtype) = v + resid(bf16 x2b)
template<int MODE>
__global__ __launch_bounds__(512) void gemm_bt(
    const ushort* __restrict__ A, const ushort* __restrict__ W,
    const float* __restrict__ bias, ushort* outb, void* outv,
    const void* resid, const int* flagp, int N, int K, int Mrows, int moff)
{
    __shared__ __align__(16) ushort As[2][256 * 32];
    __shared__ __align__(16) ushort Bs[2][128 * 32];

    const int dt   = *flagp;
    const int tid  = threadIdx.x;
    const int wid  = tid >> 6;           // 0..7
    const int lane = tid & 63;
    const int bm = blockIdx.y * 256;     // rows: y (slow)
    const int bn = blockIdx.x * 128;     // cols: x (fast) -> A-tile sharers adjacent
    const int wm = (wid >> 1) * 64;      // 0,64,128,192
    const int wn = (wid & 1) * 64;       // 0,64
    const int lrow = lane & 15;
    const int lk   = (lane >> 4) << 3;

    // staging: A chunks c=tid (rows 0..127) and c=tid+512 (rows 128..255); B chunk c=tid
    const int arow = tid >> 2;                       // 0..127
    const int koff = (tid & 3) << 3;                 // 0,8,16,24 ushorts
    const int ar0 = (bm + arow       < Mrows) ? (bm + arow)       : (Mrows - 1);
    const int ar1 = (bm + 128 + arow < Mrows) ? (bm + 128 + arow) : (Mrows - 1);
    const int brow = bn + arow;                      // always < N (N % 128 == 0)

    const ushort* pa0 = A + (size_t)ar0 * K + koff;
    const ushort* pa1 = A + (size_t)ar1 * K + koff;
    const ushort* pb  = W + (size_t)brow * K + koff;

    // bias preload BEFORE staging (extra outstanding loads only make vmcnt conservative)
    float biasf[4]; int coln[4];
    #pragma unroll
    for (int n = 0; n < 4; ++n) {
        coln[n] = bn + wn + n * 16 + lrow;
        biasf[n] = bias[coln[n]];
    }

    f32x4_t acc[4][4];
    #pragma unroll
    for (int m = 0; m < 4; ++m)
        #pragma unroll
        for (int n = 0; n < 4; ++n) acc[m][n] = (f32x4_t){0.f, 0.f, 0.f, 0.f};

    const int nk = K >> 5;
    // prologue: stage k-step 0 into buffer 0 (3 loads/thread)
    gload_lds16(pa0, As[0] + tid * 8);
    gload_lds16(pa1, As[0] + 4096 + tid * 8);
    gload_lds16(pb,  Bs[0] + tid * 8);

    int cur = 0;
    for (int kt = 0; kt < nk; ++kt) {
        if (kt + 1 < nk) {
            const int nxt = cur ^ 1;
            const int k1 = (kt + 1) << 5;
            gload_lds16(pa0 + k1, As[nxt] + tid * 8);
            gload_lds16(pa1 + k1, As[nxt] + 4096 + tid * 8);
            gload_lds16(pb  + k1, Bs[nxt] + tid * 8);
            __builtin_amdgcn_sched_barrier(0);
            asm volatile("s_waitcnt vmcnt(3)" ::: "memory");  // prev stage landed; 3 in flight
        } else {
            asm volatile("s_waitcnt vmcnt(0)" ::: "memory");
        }
        __builtin_amdgcn_s_barrier();        // #1: buf[cur] populated block-wide
        __builtin_amdgcn_sched_barrier(0);

        bf16x8_t af[4], bfr[4];
        #pragma unroll
        for (int m = 0; m < 4; ++m)
            af[m] = *(const bf16x8_t*)&As[cur][(wm + m * 16 + lrow) * 32 + lk];
        #pragma unroll
        for (int n = 0; n < 4; ++n)
            bfr[n] = *(const bf16x8_t*)&Bs[cur][(wn + n * 16 + lrow) * 32 + lk];
        #pragma unroll
        for (int m = 0; m < 4; ++m)
            #pragma unroll
            for (int n = 0; n < 4; ++n)
                acc[m][n] = __builtin_amdgcn_mfma_f32_16x16x32_bf16(
                    af[m], bfr[n], acc[m][n], 0, 0, 0);

        __builtin_amdgcn_sched_barrier(0);
        __builtin_amdgcn_s_barrier();        // #2: all reads of buf[cur] done
        cur ^= 1;
    }

    const int rbase = bm + wm + ((lane >> 4) << 2);
    #pragma unroll
    for (int m = 0; m < 4; ++m) {
        #pragma unroll
        for (int j = 0; j < 4; ++j) {
            int grow = rbase + m * 16 + j;
            if (grow >= Mrows) continue;
            #pragma unroll
            for (int n = 0; n < 4; ++n) {
                float v = acc[m][n][j] + biasf[n];
                if (MODE == 0) {
                    outb[(size_t)grow * N + coln[n]] = f2b(v);
                } else if (MODE == 2) {
                    v = 0.5f * v * (1.0f + erff(v * 0.70710678118654752f));
                    outb[(size_t)grow * N + coln[n]] = f2b(v);
                } else if (MODE == 1) {
                    size_t oidx = (size_t)win2tok(moff + grow) * (size_t)N + coln[n];
                    outb[oidx] = f2b(v + ldin(resid, oidx, dt));
                } else {
                    size_t oidx = (size_t)(moff + grow) * (size_t)N + coln[n];
                    float r = v + b2f(((const ushort*)resid)[oidx]);
                    if (dt) ((ushort*)outv)[oidx] = f2b(r);
                    else    ((float*) outv)[oidx] = r;
                }
            }
        }
    }
}

// ---------------- MFMA windowed attention: 1 block/window, wave = 3 heads ----------------
__global__ __launch_bounds__(256) void attn_kernel(
    const ushort* __restrict__ qkv, const float* __restrict__ rpb,
    ushort* __restrict__ out, int win_off)
{
    __shared__ __align__(16) ushort Pl[4][64 * 64];   // 8KB per wave
    __shared__ __align__(16) ushort Vtl[4][32 * 64];  // 4KB per wave

    const int tid = threadIdx.x, wid = tid >> 6, lane = tid & 63;
    const int lo = lane & 15, hi = lane >> 4;
    const int widx = blockIdx.x;
    const int w_ = (win_off + widx) & 63;
    const int wh = w_ >> 3, ww = w_ & 7;
    const bool edge = (wh == 7) || (ww == 7);

    char* P  = (char*)Pl[wid];
    char* Vw = (char*)Vtl[wid];

    int qr[4], qc[4], rq[4];
    #pragma unroll
    for (int n = 0; n < 4; ++n) {
        int q = n * 16 + lo; if (q > 48) q = 48;
        qr[n] = q / 7; qc[n] = q - qr[n] * 7;
        int gh = wh * 7 + qr[n], gw = ww * 7 + qc[n];
        rq[n] = (gh < 49 ? 0 : (gh < 53 ? 1 : 2)) * 3 + (gw < 49 ? 0 : (gw < 53 ? 1 : 2));
    }

    for (int h = wid; h < HEADS; h += 4) {
        const size_t hb = (size_t)widx * 49 * QKV_N + h * HDIM;

        bf16x8_t kf[4], qf[4];
        #pragma unroll
        for (int t = 0; t < 4; ++t) {
            int r = t * 16 + lo;
            bf16x8_t z = {};
            kf[t] = z; qf[t] = z;
            if (r < 49) {
                kf[t] = *(const bf16x8_t*)(qkv + hb + (size_t)r * QKV_N + 384 + hi * 8);
                qf[t] = *(const bf16x8_t*)(qkv + hb + (size_t)r * QKV_N + hi * 8);
            }
        }

        {
            const int kk = lane;
            union { bf16x8_t v; ushort u[8]; } vv[4];
            #pragma unroll
            for (int c = 0; c < 4; ++c) {
                bf16x8_t z = {};
                vv[c].v = (kk < 49) ? *(const bf16x8_t*)(qkv + hb + (size_t)kk * QKV_N + 768 + c * 8)
                                    : z;
            }
            #pragma unroll
            for (int d = 0; d < 32; ++d) {
                int byo = (d * 128 + kk * 2) ^ ((d & 7) << 4);
                *(ushort*)(Vw + byo) = vv[d >> 3].u[d & 7];
            }
        }

        f32x4_t St[4][4];
        #pragma unroll
        for (int m = 0; m < 4; ++m)
            #pragma unroll
            for (int n = 0; n < 4; ++n) St[m][n] = (f32x4_t){0.f, 0.f, 0.f, 0.f};
        #pragma unroll
        for (int m = 0; m < 4; ++m)
            #pragma unroll
            for (int n = 0; n < 4; ++n)
                St[m][n] = __builtin_amdgcn_mfma_f32_16x16x32_bf16(kf[m], qf[n], St[m][n], 0, 0, 0);

        #pragma unroll
        for (int m = 0; m < 4; ++m) {
            #pragma unroll
            for (int j = 0; j < 4; ++j) {
                const int kk = m * 16 + hi * 4 + j;
                const int kcl = (kk > 48) ? 48 : kk;
                const int kr = kcl / 7, kc = kcl - kr * 7;
                int rk = 0;
                if (edge) {
                    int gh = wh * 7 + kr, gw = ww * 7 + kc;
                    rk = (gh < 49 ? 0 : (gh < 53 ? 1 : 2)) * 3 + (gw < 49 ? 0 : (gw < 53 ? 1 : 2));
                }
                #pragma unroll
                for (int n = 0; n < 4; ++n) {
                    int idx = (qr[n] - kr + 6) * 13 + (qc[n] - kc + 6);
                    float v = St[m][n][j] * 0.17677669529663687f + rpb[idx * 12 + h];
                    if (edge && (rq[n] != rk)) v -= 100.f;
                    if (kk > 48) v = -1e30f;
                    St[m][n][j] = v;
                }
            }
        }

        float sm[4];
        #pragma unroll
        for (int n = 0; n < 4; ++n) {
            float mv = St[0][n][0];
            #pragma unroll
            for (int m = 0; m < 4; ++m)
                #pragma unroll
                for (int j = 0; j < 4; ++j) mv = fmaxf(mv, St[m][n][j]);
            mv = fmaxf(mv, __shfl_xor(mv, 16, 64));
            mv = fmaxf(mv, __shfl_xor(mv, 32, 64));
            float sv = 0.f;
            #pragma unroll
            for (int m = 0; m < 4; ++m)
                #pragma unroll
                for (int j = 0; j < 4; ++j) {
                    float e = __expf(St[m][n][j] - mv);
                    St[m][n][j] = e; sv += e;
                }
            sv += __shfl_xor(sv, 16, 64);
            sv += __shfl_xor(sv, 32, 64);
            sm[n] = 1.f / sv;
        }

        #pragma unroll
        for (int m = 0; m < 4; ++m) {
            #pragma unroll
            for (int n = 0; n < 4; ++n) {
                union { ushort4 u4; __bf16 b[4]; } pk;
                #pragma unroll
                for (int j = 0; j < 4; ++j) pk.b[j] = (__bf16)(St[m][n][j] * sm[n]);
                int byo = ((n * 16 + lo) * 128 + (m * 16 + hi * 4) * 2) ^ ((lo & 7) << 4);
                *(ushort4*)(P + byo) = pk.u4;
            }
        }

        f32x4_t Oa[4][2];
        #pragma unroll
        for (int mt = 0; mt < 4; ++mt)
            #pragma unroll
            for (int nt = 0; nt < 2; ++nt) Oa[mt][nt] = (f32x4_t){0.f, 0.f, 0.f, 0.f};
        #pragma unroll
        for (int s = 0; s < 2; ++s) {
            bf16x8_t vf[2];
            #pragma unroll
            for (int nt = 0; nt < 2; ++nt) {
                int byo = ((nt * 16 + lo) * 128 + s * 64 + hi * 16) ^ ((lo & 7) << 4);
                vf[nt] = *(const bf16x8_t*)(Vw + byo);
            }
            #pragma unroll
            for (int mt = 0; mt < 4; ++mt) {
                int byo = ((mt * 16 + lo) * 128 + s * 64 + hi * 16) ^ ((lo & 7) << 4);
                bf16x8_t pf = *(const bf16x8_t*)(P + byo);
                #pragma unroll
                for (int nt = 0; nt < 2; ++nt)
                    Oa[mt][nt] = __builtin_amdgcn_mfma_f32_16x16x32_bf16(pf, vf[nt], Oa[mt][nt], 0, 0, 0);
            }
        }

        #pragma unroll
        for (int mt = 0; mt < 4; ++mt) {
            #pragma unroll
            for (int j = 0; j < 4; ++j) {
                int q = mt * 16 + hi * 4 + j;
                if (q < 49) {
                    size_t ro = ((size_t)(widx * 49 + q)) * C_DIM + h * HDIM;
                    #pragma unroll
                    for (int nt = 0; nt < 2; ++nt)
                        out[ro + nt * 16 + lo] = f2b(Oa[mt][nt][j]);
                }
            }
        }
    }
}

// ---------------- launch ----------------
extern "C" void kernel_launch(void* const* d_in, const int* in_sizes, int n_in,
                              void* d_out, int out_size, void* d_ws, size_t ws_size,
                              hipStream_t stream)
{
    const void* x      = d_in[0];
    const void* n1g    = d_in[3];
    const void* n1b    = d_in[4];
    const void* qkv_w  = d_in[5];
    const void* qkv_b  = d_in[6];
    const void* rpb    = d_in[7];
    const void* proj_w = d_in[8];
    const void* proj_b = d_in[9];
    const void* n2g    = d_in[10];
    const void* n2b    = d_in[11];
    const void* fc1_w  = d_in[12];
    const void* fc1_b  = d_in[13];
    const void* fc2_w  = d_in[14];
    const void* fc2_b  = d_in[15];

    // ws: 0 flag | 256 prm f32 | 28416 weights bf16 | WSTATIC: x2b (full, bf16) | ws0 | ws1
    int*    flagp = (int*)d_ws;
    float*  prm   = (float*)((char*)d_ws + 256);
    ushort* wq    = (ushort*)((char*)d_ws + 28416);
    ushort* wp    = wq + 442368;
    ushort* w1m   = wp + 147456;
    ushort* w2m   = w1m + 589824;
    const size_t WSTATIC = 3567360;
    const size_t X2B_B   = 77070336ull;               // M_TOK*384*2

    int nc = 64;
    const int opts[7] = {1, 2, 4, 8, 16, 32, 64};
    for (int i = 0; i < 7; ++i) {
        size_t need = WSTATIC + X2B_B + ((size_t)M_TOK / opts[i]) * 3840ull;
        if (need <= ws_size) { nc = opts[i]; break; }
    }
    const int wins_pc = TOT_WIN / nc;
    const int rows_pc = wins_pc * NTOK;
    const int gx      = (rows_pc + 255) / 256;        // 256-row tiles now

    ushort* x2b = (ushort*)((char*)d_ws + WSTATIC);   // full M_TOK x 384 bf16
    ushort* ws0 = x2b + (size_t)M_TOK * C_DIM;
    ushort* ws1 = ws0 + (size_t)rows_pc * C_DIM;

    sniff_kernel<<<1, 256, 0, stream>>>((const ushort*)x, flagp);
    cvt_p_kernel<<<1, 256, 0, stream>>>(n1g, n1b, qkv_b, proj_b, n2g, n2b,
                                        fc1_b, fc2_b, rpb, prm, flagp);
    cvt_w_kernel<<<432, 256, 0, stream>>>(qkv_w,  wq,  442368, flagp);
    cvt_w_kernel<<<144, 256, 0, stream>>>(proj_w, wp,  147456, flagp);
    cvt_w_kernel<<<576, 256, 0, stream>>>(fc1_w,  w1m, 589824, flagp);
    cvt_w_kernel<<<576, 256, 0, stream>>>(fc2_w,  w2m, 589824, flagp);

    const float* b_qkv = prm + 768;
    const float* b_prj = prm + 1920;
    const float* b_fc1 = prm + 3072;
    const float* b_fc2 = prm + 4608;
    const float* rpb_c = prm + 4992;

    for (int c = 0; c < nc; ++c) {
        const int moff = c * rows_pc;
        ln_kernel<0><<<rows_pc / 4, 256, 0, stream>>>(x, prm + 0, prm + 384, ws0, flagp, moff);
        gemm_bt<0><<<dim3(9, gx), 512, 0, stream>>>(
            ws0, wq, b_qkv, ws1, nullptr, nullptr, flagp, QKV_N, C_DIM, rows_pc, 0);
        attn_kernel<<<wins_pc, 256, 0, stream>>>(ws1, rpb_c, ws0, c * wins_pc);
        // PROJ: x2b(bf16, scattered global rows) = proj(attn) + shortcut(native x)
        gemm_bt<1><<<dim3(3, gx), 512, 0, stream>>>(
            ws0, wp, b_prj, x2b, nullptr, x, flagp, C_DIM, C_DIM, rows_pc, moff);
    }

    for (int c = 0; c < nc; ++c) {
        const int moff = c * rows_pc;
        // LN2 reads bf16 x2b (global rows moff+m)
        ln_kernel<2><<<rows_pc / 4, 256, 0, stream>>>(x2b, prm + 2304, prm + 2688, ws0, flagp, moff);
        gemm_bt<2><<<dim3(12, gx), 512, 0, stream>>>(
            ws0, w1m, b_fc1, ws1, nullptr, nullptr, flagp, MLP_N, C_DIM, rows_pc, 0);
        // FC2: d_out(native, global rows moff+grow) = fc2(h1) + x2b(bf16)
        gemm_bt<3><<<dim3(3, gx), 512, 0, stream>>>(
            ws1, w2m, b_fc2, nullptr, d_out, x2b, flagp, C_DIM, MLP_N, rows_pc, moff);
    }
}